// Round 15
// baseline (66.769 us; speedup 1.0000x reference)
//
#include <hip/hip_runtime.h>
#include <hip/hip_bf16.h>

#define BB 4096
#define DD 512
#define NB_N2O 512
#define NB_N2N 272
#define NBLK 784
// partial slots: 0..31 n2o(nt) | 32..63 n2n row-i (cj) | 64..79 n2n row-j (ri)

typedef unsigned short u16;
typedef unsigned int u32;
typedef signed char s8;

using f32x4 = __attribute__((ext_vector_type(4))) float;
using i32x4 = __attribute__((ext_vector_type(4))) int;

// int8 quant: q = rint(x_norm * QS); exact i32 dot, s ~= acc / QS^2.
// p = exp2((s-1)*100*log2e + 64) = exp2(acc*CEXPQ + EOFF); lse = 100 - 64*ln2 + ln(sum p)
constexpr float QS = 400.0f;
constexpr float CEXP = 144.26950408889634f;          // 100 * log2(e)
constexpr float CEXPQ = CEXP / (QS * QS);            // dequant folded in
constexpr float EOFF = 64.0f - 144.26950408889634f;  // bias - CEXP
constexpr float LN2 = 0.6931471805599453f;
constexpr float LSE_BASE = 100.0f - 64.0f * 0.6931471805599453f;

__device__ __forceinline__ float wave_sum(float v) {
#pragma unroll
  for (int m = 1; m < 64; m <<= 1) v += __shfl_xor(v, m);
  return v;
}

// async global->LDS, 16B per lane. LDS dest is wave-uniform base + lane*16.
__device__ __forceinline__ void gload16(const void* g, const void* l) {
  __builtin_amdgcn_global_load_lds(
      (const __attribute__((address_space(1))) void*)g,
      (__attribute__((address_space(3))) void*)(const_cast<void*>(l)), 16, 0, 0);
}

// raw barrier (no vmcnt/lgkmcnt drain); memory clobbers pin memory ops to their side
__device__ __forceinline__ void barrier_raw() {
  asm volatile("" ::: "memory");
  __builtin_amdgcn_s_barrier();
  asm volatile("" ::: "memory");
}

__device__ __forceinline__ u32 q4(float a, float b, float c, float d, float s) {
  const int qa = (int)rintf(fminf(fmaxf(a * s, -127.0f), 127.0f));
  const int qb = (int)rintf(fminf(fmaxf(b * s, -127.0f), 127.0f));
  const int qc = (int)rintf(fminf(fmaxf(c * s, -127.0f), 127.0f));
  const int qd = (int)rintf(fminf(fmaxf(d * s, -127.0f), 127.0f));
  return (qa & 0xff) | ((qb & 0xff) << 8) | ((qc & 0xff) << 16) | ((qd & 0xff) << 24);
}

// ---------------- kernel 1: L2-normalize -> int8; zero slot-major partial ----------------
__global__ __launch_bounds__(256) void k_norm(const float* __restrict__ feat,
                                              const float* __restrict__ feat_old,
                                              s8* __restrict__ fn8, s8* __restrict__ fo8,
                                              float* __restrict__ pos,
                                              float* __restrict__ partial) {
  // zero partial[80][4096]: 81920 float4 = 1024 blocks x 80
  if (threadIdx.x < 80) {
    float4 z; z.x = z.y = z.z = z.w = 0.0f;
    ((float4*)partial)[(size_t)blockIdx.x * 80 + threadIdx.x] = z;
  }
  const int i = blockIdx.x * 4 + (threadIdx.x >> 6);
  const int t = threadIdx.x & 63;
  const float4 x0 = *(const float4*)(feat + (size_t)i * DD + t * 4);
  const float4 x1 = *(const float4*)(feat + (size_t)i * DD + 256 + t * 4);
  const float4 y0 = *(const float4*)(feat_old + (size_t)i * DD + t * 4);
  const float4 y1 = *(const float4*)(feat_old + (size_t)i * DD + 256 + t * 4);
  float sx = x0.x * x0.x + x0.y * x0.y + x0.z * x0.z + x0.w * x0.w +
             x1.x * x1.x + x1.y * x1.y + x1.z * x1.z + x1.w * x1.w;
  float sy = y0.x * y0.x + y0.y * y0.y + y0.z * y0.z + y0.w * y0.w +
             y1.x * y1.x + y1.y * y1.y + y1.z * y1.z + y1.w * y1.w;
  float sxy = x0.x * y0.x + x0.y * y0.y + x0.z * y0.z + x0.w * y0.w +
              x1.x * y1.x + x1.y * y1.y + x1.z * y1.z + x1.w * y1.w;
  sx = wave_sum(sx);
  sy = wave_sum(sy);
  sxy = wave_sum(sxy);
  const float inx = 1.0f / fmaxf(sqrtf(sx), 1e-12f);
  const float iny = 1.0f / fmaxf(sqrtf(sy), 1e-12f);
  const float sxq = inx * QS, syq = iny * QS;
  u32* px0 = (u32*)(fn8 + (size_t)i * DD + t * 4);
  u32* px1 = (u32*)(fn8 + (size_t)i * DD + 256 + t * 4);
  u32* py0 = (u32*)(fo8 + (size_t)i * DD + t * 4);
  u32* py1 = (u32*)(fo8 + (size_t)i * DD + 256 + t * 4);
  *px0 = q4(x0.x, x0.y, x0.z, x0.w, sxq);
  *px1 = q4(x1.x, x1.y, x1.z, x1.w, sxq);
  *py0 = q4(y0.x, y0.y, y0.z, y0.w, syq);
  *py1 = q4(y1.x, y1.y, y1.z, y1.w, syq);
  if (t == 0) pos[i] = sxy * inx * iny;  // exact fp32 positive logit
}

// ---------------- kernel 2: fused dual-GEMM, n2n triangle, slot writes ----------------
// Blocks 0..511: n2o 256x128 tiles (fn x fo), XCD-swizzled. Blocks 512..783: n2n
// strict-upper tiles (ri: 16 row-tiles of 256, cj: 32 col-tiles of 128, cj >= 2*ri):
// each unordered pair {i<j} computed ONCE; contributes to row i (col-reduce, slot 32+cj)
// AND row j (transpose row-reduce across waves via LDS, slot 64+ri).
// 512 threads = 8 waves (wm = wid&3 M-quarter 64 rows; wn = wid>>2 N-half 64 cols);
// acc 4x4 i32x4 = 64 regs (R10-proven register profile, NO spill; R13's 256-thread
// variant spilled acc to scratch -> 218MB scratch writes).
// R9-proven loop: BK=64, LDS dbuf 48KB, gload_lds pre-swizzled source, vmcnt(2) gate.
// All partial writes are plain stores to slot-private regions (no atomics; R12 showed
// per-row device atomics -> 59MB coherence ping-pong, 167us). Cross-XCD visibility
// via the kernel boundary before k_final.
__global__ __launch_bounds__(512, 4) void k_fused(const s8* __restrict__ fn8,
                                                  const s8* __restrict__ fo8,
                                                  const int* __restrict__ tgt,
                                                  float* __restrict__ partial) {
  __shared__ __align__(16) s8 lA[2][256 * 64];  // 32 KB
  __shared__ __align__(16) s8 lB[2][128 * 64];  // 16 KB

  const int tid = threadIdx.x;
  const int lane = tid & 63;
  const int wid = tid >> 6;  // 0..7
  const int wm = wid & 3;    // M quarter (64 rows)
  const int wn = wid >> 2;   // N half (64 cols)
  const int lrow = lane & 15;
  const int lkg = lane >> 4;

  // ---- block -> tile mapping ----
  const int flat = blockIdx.x;
  const bool isN2O = (flat < NB_N2O);
  int row0, jb, ri = 0, cj = 0;
  const s8* bsrc;
  if (isN2O) {
    const int swz = (flat & 7) * 64 + (flat >> 3);  // bijective (512%8==0)
    row0 = (swz >> 5) * 256;
    jb = (swz & 31) * 128;
    bsrc = fo8;
  } else {
    int idx = flat - NB_N2O;  // 0..271 -> (ri, cj), cj >= 2*ri  [R12/R13-verified]
    int r = 0;
    while (idx >= (r + 1) * (32 - r)) ++r;
    ri = r;
    cj = 2 * r + (idx - r * (33 - r));
    row0 = ri * 256;
    jb = cj * 128;
    bsrc = fn8;
  }

  // staging: chunk = 16 rows x 64 B = 64 lanes x 16 B; source slot pre-swizzled so the
  // linear LDS write lands in read-swizzled position (read slot' = slot ^ ((row>>1)&3)).
  const int crow = lane >> 2;
  const int cofs = 16 * ((lane & 3) ^ ((lane >> 3) & 3));

  auto stageA = [&](s8* dst, int kk) {  // 16 chunks cover 256 A rows; 2/wave
#pragma unroll
    for (int i = 0; i < 2; ++i) {
      const int c = wid * 2 + i;
      gload16(fn8 + (size_t)(row0 + c * 16 + crow) * DD + kk + cofs, dst + c * 1024);
    }
  };
  auto stageB = [&](s8* dst, int kk) {  // 8 chunks cover 128 B rows; 1/wave
    gload16(bsrc + (size_t)(jb + wid * 16 + crow) * DD + kk + cofs, dst + wid * 1024);
  };

  i32x4 acc[4][4];
#pragma unroll
  for (int a = 0; a < 4; ++a)
#pragma unroll
    for (int b = 0; b < 4; ++b) acc[a][b] = (i32x4)(0);

  // prologue: tile 0 (3 loads/wave in flight)
  stageA(lA[0], 0);
  stageB(lB[0], 0);

  for (int t = 0; t < 8; ++t) {
    const int cur = t & 1, nxt = cur ^ 1;
    const s8* cA = lA[cur];
    const s8* cB = lB[cur];

    if (t < 7) {
      stageA(lA[nxt], (t + 1) * 64);                  // 2 new; 5 outstanding
      asm volatile("s_waitcnt vmcnt(2)" ::: "memory");  // tile t's 3 landed
    } else {
      asm volatile("s_waitcnt vmcnt(0)" ::: "memory");
    }
    barrier_raw();

    i32x4 av[4], bv[4];
#pragma unroll
    for (int f = 0; f < 4; ++f) {
      const int ar = wm * 64 + f * 16 + lrow;
      av[f] = *(const i32x4*)(cA + ar * 64 + ((lkg ^ ((ar >> 1) & 3)) * 16));
    }
#pragma unroll
    for (int f = 0; f < 4; ++f) {
      const int br = wn * 64 + f * 16 + lrow;
      bv[f] = *(const i32x4*)(cB + br * 64 + ((lkg ^ ((br >> 1) & 3)) * 16));
    }
    if (t < 7) stageB(lB[nxt], (t + 1) * 64);
    __builtin_amdgcn_s_setprio(1);
#pragma unroll
    for (int fr = 0; fr < 4; ++fr)
#pragma unroll
      for (int fc = 0; fc < 4; ++fc)
        acc[fr][fc] = __builtin_amdgcn_mfma_i32_16x16x64_i8(av[fr], bv[fc], acc[fr][fc], 0, 0, 0);
    __builtin_amdgcn_s_setprio(0);
    barrier_raw();
  }

  // ---- epilogue: dequant + masked exp2 -> slot-private row sums ----
  int tc[4];
#pragma unroll
  for (int fc = 0; fc < 4; ++fc) tc[fc] = tgt[jb + wn * 64 + fc * 16 + lrow];
  float* fbuf = (float*)lA;  // 4 KB scratch; loop's trailing barrier freed lA

  if (isN2O) {
    // col-reduce; keep diagonal (stands in for the explicit pos column)
#pragma unroll
    for (int fr = 0; fr < 4; ++fr) {
#pragma unroll
      for (int reg = 0; reg < 4; ++reg) {
        const int gr = row0 + wm * 64 + fr * 16 + lkg * 4 + reg;
        const int trv = tgt[gr];
        float s = 0.0f;
#pragma unroll
        for (int fc = 0; fc < 4; ++fc) {
          const int gc = jb + wn * 64 + fc * 16 + lrow;
          const float p = __builtin_amdgcn_exp2f(fmaf((float)acc[fr][fc][reg], CEXPQ, EOFF));
          const bool keep = (trv != tc[fc]) || (gr == gc);
          s += keep ? p : 0.0f;
        }
        s += __shfl_xor(s, 1);
        s += __shfl_xor(s, 2);
        s += __shfl_xor(s, 4);
        s += __shfl_xor(s, 8);
        if (lrow == 0) fbuf[wn * 256 + wm * 64 + fr * 16 + lkg * 4 + reg] = s;
      }
    }
    asm volatile("s_waitcnt lgkmcnt(0)" ::: "memory");
    barrier_raw();
    if (tid < 256) {
      const int nt = jb >> 7;
      partial[(size_t)nt * BB + row0 + tid] = fbuf[tid] + fbuf[256 + tid];
    }
  } else {
    // n2n upper-triangle: keep = (gr<gc) && labels differ; contribute BOTH ways
    float tv[4] = {0.0f, 0.0f, 0.0f, 0.0f};
#pragma unroll
    for (int fr = 0; fr < 4; ++fr) {
#pragma unroll
      for (int reg = 0; reg < 4; ++reg) {
        const int gr = row0 + wm * 64 + fr * 16 + lkg * 4 + reg;
        const int trv = tgt[gr];
        float s = 0.0f;
#pragma unroll
        for (int fc = 0; fc < 4; ++fc) {
          const int gc = jb + wn * 64 + fc * 16 + lrow;
          const float p = __builtin_amdgcn_exp2f(fmaf((float)acc[fr][fc][reg], CEXPQ, EOFF));
          const float pk = ((gr < gc) && (trv != tc[fc])) ? p : 0.0f;
          s += pk;
          tv[fc] += pk;
        }
        s += __shfl_xor(s, 1);
        s += __shfl_xor(s, 2);
        s += __shfl_xor(s, 4);
        s += __shfl_xor(s, 8);
        if (lrow == 0) fbuf[wn * 256 + wm * 64 + fr * 16 + lkg * 4 + reg] = s;  // row-i
      }
    }
    // transpose side: reduce tv over the wave's 4 lkg row-groups, stash per wave
#pragma unroll
    for (int fc = 0; fc < 4; ++fc) {
      tv[fc] += __shfl_xor(tv[fc], 16);
      tv[fc] += __shfl_xor(tv[fc], 32);
    }
    if (lane < 16) {
#pragma unroll
      for (int fc = 0; fc < 4; ++fc)
        fbuf[512 + wm * 128 + wn * 64 + fc * 16 + lane] = tv[fc];
    }
    asm volatile("s_waitcnt lgkmcnt(0)" ::: "memory");
    barrier_raw();
    if (tid < 256)  // row-i side: combine the two wn halves
      partial[(size_t)(32 + cj) * BB + row0 + tid] = fbuf[tid] + fbuf[256 + tid];
    else if (tid < 384) {  // row-j side: combine the four wm quarters
      const int c = tid - 256;
      const float v = fbuf[512 + c] + fbuf[512 + 128 + c] + fbuf[512 + 256 + c] +
                      fbuf[512 + 384 + c];
      partial[(size_t)(64 + ri) * BB + jb + c] = v;
    }
  }
}

// ---------------- kernel 3: per-row finalize (32 blocks) ----------------
__global__ __launch_bounds__(256) void k_final(const float* __restrict__ partial,
                                               const float* __restrict__ pos,
                                               float* __restrict__ bsum) {
  const int t = threadIdx.x;
  const int r = blockIdx.x * 128 + (t >> 1);
  const int half = t & 1;
  float v = 0.0f;
#pragma unroll
  for (int s = 0; s < 40; ++s) v += partial[(size_t)(half * 40 + s) * BB + r];
  v += __shfl_xor(v, 1);  // combine the two slot-halves of the row
  float contrib = (half == 0)
                      ? (LSE_BASE + __builtin_amdgcn_logf(v) * LN2 - 100.0f * pos[r])
                      : 0.0f;
  contrib = wave_sum(contrib);
  __shared__ float red[4];
  if ((t & 63) == 0) red[t >> 6] = contrib;
  __syncthreads();
  if (t == 0) bsum[blockIdx.x] = (red[0] + red[1]) + (red[2] + red[3]);
}

// ---------------- kernel 4: mean of 32 block sums ----------------
__global__ __launch_bounds__(64) void k_mean(const float* __restrict__ bsum,
                                             float* __restrict__ out) {
  float s = (threadIdx.x < 32) ? bsum[threadIdx.x] : 0.0f;
  s = wave_sum(s);
  if (threadIdx.x == 0) out[0] = s * (1.0f / (float)BB);
}

extern "C" void kernel_launch(void* const* d_in, const int* in_sizes, int n_in,
                              void* d_out, int out_size, void* d_ws, size_t ws_size,
                              hipStream_t stream) {
  const float* feat = (const float*)d_in[0];
  const float* feat_old = (const float*)d_in[1];
  const int* targets = (const int*)d_in[2];
  float* out = (float*)d_out;
  char* ws = (char*)d_ws;

  s8* fn8 = (s8*)ws;                                             // 2 MB
  s8* fo8 = (s8*)(ws + 2u * 1024 * 1024);                        // 2 MB
  float* pos = (float*)(ws + 4u * 1024 * 1024);                  // 16 KB
  float* partial = (float*)(ws + 4u * 1024 * 1024 + 16 * 1024);  // 80*4096*4 = 1.25 MB
  float* bsum = (float*)(ws + 6u * 1024 * 1024);                 // 128 B

  k_norm<<<BB / 4, 256, 0, stream>>>(feat, feat_old, fn8, fo8, pos, partial);
  k_fused<<<NBLK, 512, 0, stream>>>(fn8, fo8, targets, partial);
  k_final<<<32, 256, 0, stream>>>(partial, pos, bsum);
  k_mean<<<1, 64, 0, stream>>>(bsum, out);
}

// Round 16
// 43.989 us; speedup vs baseline: 1.5179x; 1.5179x over previous
//
#include <hip/hip_runtime.h>
#include <hip/hip_bf16.h>

#define BB 4096
#define DD 512

typedef unsigned short u16;
typedef unsigned int u32;
typedef signed char s8;

using f32x4 = __attribute__((ext_vector_type(4))) float;
using i32x4 = __attribute__((ext_vector_type(4))) int;

// int8 quant: q = rint(x_norm * QS); exact i32 dot, s ~= acc / QS^2.
// p = exp2((s-1)*100*log2e + 64) = exp2(acc*CEXPQ + EOFF); lse = 100 - 64*ln2 + ln(sum p)
constexpr float QS = 400.0f;
constexpr float CEXP = 144.26950408889634f;          // 100 * log2(e)
constexpr float CEXPQ = CEXP / (QS * QS);            // dequant folded in
constexpr float EOFF = 64.0f - 144.26950408889634f;  // bias - CEXP
constexpr float LN2 = 0.6931471805599453f;
constexpr float LSE_BASE = 100.0f - 64.0f * 0.6931471805599453f;

__device__ __forceinline__ float wave_sum(float v) {
#pragma unroll
  for (int m = 1; m < 64; m <<= 1) v += __shfl_xor(v, m);
  return v;
}

// async global->LDS, 16B per lane. LDS dest is wave-uniform base + lane*16.
__device__ __forceinline__ void gload16(const void* g, const void* l) {
  __builtin_amdgcn_global_load_lds(
      (const __attribute__((address_space(1))) void*)g,
      (__attribute__((address_space(3))) void*)(const_cast<void*>(l)), 16, 0, 0);
}

// raw barrier (no vmcnt/lgkmcnt drain); memory clobbers pin memory ops to their side
__device__ __forceinline__ void barrier_raw() {
  asm volatile("" ::: "memory");
  __builtin_amdgcn_s_barrier();
  asm volatile("" ::: "memory");
}

__device__ __forceinline__ u32 q4(float a, float b, float c, float d, float s) {
  const int qa = (int)rintf(fminf(fmaxf(a * s, -127.0f), 127.0f));
  const int qb = (int)rintf(fminf(fmaxf(b * s, -127.0f), 127.0f));
  const int qc = (int)rintf(fminf(fmaxf(c * s, -127.0f), 127.0f));
  const int qd = (int)rintf(fminf(fmaxf(d * s, -127.0f), 127.0f));
  return (qa & 0xff) | ((qb & 0xff) << 8) | ((qc & 0xff) << 16) | ((qd & 0xff) << 24);
}

// ---------------- kernel 1: row L2-normalize (fp32) -> int8 (scale QS), fp32 pos ----------------
__global__ __launch_bounds__(256) void k_norm(const float* __restrict__ feat,
                                              const float* __restrict__ feat_old,
                                              s8* __restrict__ fn8, s8* __restrict__ fo8,
                                              float* __restrict__ pos) {
  const int i = blockIdx.x * 4 + (threadIdx.x >> 6);
  const int t = threadIdx.x & 63;
  const float4 x0 = *(const float4*)(feat + (size_t)i * DD + t * 4);
  const float4 x1 = *(const float4*)(feat + (size_t)i * DD + 256 + t * 4);
  const float4 y0 = *(const float4*)(feat_old + (size_t)i * DD + t * 4);
  const float4 y1 = *(const float4*)(feat_old + (size_t)i * DD + 256 + t * 4);
  float sx = x0.x * x0.x + x0.y * x0.y + x0.z * x0.z + x0.w * x0.w +
             x1.x * x1.x + x1.y * x1.y + x1.z * x1.z + x1.w * x1.w;
  float sy = y0.x * y0.x + y0.y * y0.y + y0.z * y0.z + y0.w * y0.w +
             y1.x * y1.x + y1.y * y1.y + y1.z * y1.z + y1.w * y1.w;
  float sxy = x0.x * y0.x + x0.y * y0.y + x0.z * y0.z + x0.w * y0.w +
              x1.x * y1.x + x1.y * y1.y + x1.z * y1.z + x1.w * y1.w;
  sx = wave_sum(sx);
  sy = wave_sum(sy);
  sxy = wave_sum(sxy);
  const float inx = 1.0f / fmaxf(sqrtf(sx), 1e-12f);
  const float iny = 1.0f / fmaxf(sqrtf(sy), 1e-12f);
  const float sxq = inx * QS, syq = iny * QS;
  u32* px0 = (u32*)(fn8 + (size_t)i * DD + t * 4);
  u32* px1 = (u32*)(fn8 + (size_t)i * DD + 256 + t * 4);
  u32* py0 = (u32*)(fo8 + (size_t)i * DD + t * 4);
  u32* py1 = (u32*)(fo8 + (size_t)i * DD + 256 + t * 4);
  *px0 = q4(x0.x, x0.y, x0.z, x0.w, sxq);
  *px1 = q4(x1.x, x1.y, x1.z, x1.w, sxq);
  *py0 = q4(y0.x, y0.y, y0.z, y0.w, syq);
  *py1 = q4(y1.x, y1.y, y1.z, y1.w, syq);
  if (t == 0) pos[i] = sxy * inx * iny;  // exact fp32 positive logit
}

// ---------------- kernel 2: fused dual-GEMM, int8 MFMA (R9 champion + unroll) ----------------
// 512 blocks = 16 mt x 32 nt (XCD-swizzled, EXACTLY 2 rounds of 256 CUs - no tail).
// 512 threads = 8 waves: wr = wid&3 (64-row M quarter), sel = wid>>2 (B1=old / B2=new).
// Tile: A 256xK, B 128xK each. BK=64 -> 32 mfma_i32_16x16x64_i8 per wave per K-tile.
// LDS 64 KB dbuf (2 blocks/CU co-resident with VGPR<=128). K-loop FULLY UNROLLED:
// static buffer selects, immediate ds/LDS offsets. All 4 stage loads issue at the top
// of the iteration (safe: end-of-iter barrier of t-1 means no wave still reads
// buf[nxt]); vmcnt(4) gates tile t's 4 loads with 4 new in flight, never draining.
__global__ __launch_bounds__(512, 2) void k_fused(const s8* __restrict__ fn8,
                                                  const s8* __restrict__ fo8,
                                                  const int* __restrict__ tgt,
                                                  float* __restrict__ partial) {
  __shared__ __align__(16) s8 lA[2][256 * 64];   // 32 KB
  __shared__ __align__(16) s8 lB1[2][128 * 64];  // 16 KB
  __shared__ __align__(16) s8 lB2[2][128 * 64];  // 16 KB

  const int tid = threadIdx.x;
  const int lane = tid & 63;
  const int wid = tid >> 6;   // 0..7
  const int wr = wid & 3;     // M quarter
  const int sel = wid >> 2;   // 0: B1(old)  1: B2(new)
  const int lrow = lane & 15;
  const int lkg = lane >> 4;

  // XCD-aware bijective swizzle (512 % 8 == 0)
  const int flat = blockIdx.x;
  const int swz = (flat & 7) * 64 + (flat >> 3);
  const int mt = swz >> 5, nt = swz & 31;
  const int row0 = mt * 256, jb = nt * 128;

  // staging: chunk = 16 rows x 64 B = 64 lanes x 16 B. lane l covers row 16c+(l>>2),
  // phys slot l&3; fetch LOGICAL slot (l&3)^((l>>3)&3) so the linear LDS write lands
  // in read-swizzled position (read: slot' = slot ^ ((row>>1)&3), row = 16c+(l>>2)).
  const int crow = lane >> 2;
  const int cofs = 16 * ((lane & 3) ^ ((lane >> 3) & 3));

  auto stageA = [&](s8* dst, int kk) {
#pragma unroll
    for (int i = 0; i < 2; ++i) {
      const int c = wid * 2 + i;  // 16 chunks cover 256 A rows
      gload16(fn8 + (size_t)(row0 + c * 16 + crow) * DD + kk + cofs, dst + c * 1024);
    }
  };
  auto stageB = [&](s8* d1, s8* d2, int kk) {
    const int c = wid;  // 8 chunks cover 128 B rows
    gload16(fo8 + (size_t)(jb + c * 16 + crow) * DD + kk + cofs, d1 + c * 1024);
    gload16(fn8 + (size_t)(jb + c * 16 + crow) * DD + kk + cofs, d2 + c * 1024);
  };

  i32x4 acc[4][8];
#pragma unroll
  for (int a = 0; a < 4; ++a)
#pragma unroll
    for (int b = 0; b < 8; ++b) acc[a][b] = (i32x4)(0);

  // prologue: stage tile 0 (4 loads/wave in flight)
  stageA(lA[0], 0);
  stageB(lB1[0], lB2[0], 0);

#pragma unroll
  for (int t = 0; t < 8; ++t) {
    const int cur = t & 1, nxt = cur ^ 1;  // compile-time after unroll
    const s8* cA = lA[cur];
    const s8* cB = sel ? lB2[cur] : lB1[cur];

    if (t < 7) {
      // issue ALL of tile t+1's loads up front (deep prefetch; WAR-safe via the
      // end-of-iteration barrier of t-1 -- no wave still reads buf[nxt])
      stageA(lA[nxt], (t + 1) * 64);
      stageB(lB1[nxt], lB2[nxt], (t + 1) * 64);
      asm volatile("s_waitcnt vmcnt(4)" ::: "memory");  // tile t's 4 landed; 4 fly on
    } else {
      asm volatile("s_waitcnt vmcnt(0)" ::: "memory");
    }
    barrier_raw();  // gate: tile t visible everywhere; prev reads done (end barrier)

    i32x4 av[4], bv[8];
#pragma unroll
    for (int f = 0; f < 4; ++f) {
      const int ar = wr * 64 + f * 16 + lrow;
      av[f] = *(const i32x4*)(cA + ar * 64 + ((lkg ^ ((ar >> 1) & 3)) * 16));
    }
#pragma unroll
    for (int f = 0; f < 8; ++f) {
      const int br = f * 16 + lrow;
      bv[f] = *(const i32x4*)(cB + br * 64 + ((lkg ^ ((br >> 1) & 3)) * 16));
    }
    __builtin_amdgcn_s_setprio(1);
#pragma unroll
    for (int fr = 0; fr < 4; ++fr)
#pragma unroll
      for (int fc = 0; fc < 8; ++fc)
        acc[fr][fc] = __builtin_amdgcn_mfma_i32_16x16x64_i8(av[fr], bv[fc], acc[fr][fc], 0, 0, 0);
    __builtin_amdgcn_s_setprio(0);
    barrier_raw();  // all waves done reading buf[cur] before t+1 overwrites it
  }

  // ---- epilogue: dequant + masked exp2, col-reduce, combine B1+B2, store partial ----
  const bool isN2O = (sel == 0);
  int tc[8];
#pragma unroll
  for (int fc = 0; fc < 8; ++fc) tc[fc] = tgt[jb + fc * 16 + lrow];
  float* rsum = (float*)lA;  // 2*256 floats; staging reads done
#pragma unroll
  for (int fr = 0; fr < 4; ++fr) {
#pragma unroll
    for (int reg = 0; reg < 4; ++reg) {
      const int gr = row0 + wr * 64 + fr * 16 + lkg * 4 + reg;
      const int trv = tgt[gr];
      float s = 0.0f;
#pragma unroll
      for (int fc = 0; fc < 8; ++fc) {
        const int gc = jb + fc * 16 + lrow;
        const float p = __builtin_amdgcn_exp2f(fmaf((float)acc[fr][fc][reg], CEXPQ, EOFF));
        // n2o: keep diagonal (stands in for the explicit pos column), drop same-label
        // n2n: drop all same-label (diagonal auto-dropped, labels equal)
        const bool keep = (trv != tc[fc]) || (isN2O && gr == gc);
        s += keep ? p : 0.0f;
      }
      s += __shfl_xor(s, 1);
      s += __shfl_xor(s, 2);
      s += __shfl_xor(s, 4);
      s += __shfl_xor(s, 8);
      if (lrow == 0) rsum[sel * 256 + wr * 64 + fr * 16 + lkg * 4 + reg] = s;
    }
  }
  asm volatile("s_waitcnt lgkmcnt(0)" ::: "memory");
  barrier_raw();
  if (tid < 256) {
    const float v = rsum[tid] + rsum[256 + tid];
    partial[(size_t)(row0 + tid) * 32 + nt] = v;
  }
}

// ---------------- kernel 3: per-row finalize (32 blocks) ----------------
__global__ __launch_bounds__(256) void k_final(const float* __restrict__ partial,
                                               const float* __restrict__ pos,
                                               float* __restrict__ bsum) {
  const int t = threadIdx.x;
  const int r = blockIdx.x * 128 + (t >> 1);
  const int half = t & 1;
  const float4* p = (const float4*)(partial + (size_t)r * 32 + half * 16);
  float v = 0.0f;
#pragma unroll
  for (int q = 0; q < 4; ++q) {
    const float4 a = p[q];
    v += (a.x + a.y) + (a.z + a.w);
  }
  v += __shfl_xor(v, 1);  // combine the two halves of the row
  float contrib = (half == 0)
                      ? (LSE_BASE + __builtin_amdgcn_logf(v) * LN2 - 100.0f * pos[r])
                      : 0.0f;
  contrib = wave_sum(contrib);
  __shared__ float red[4];
  if ((t & 63) == 0) red[t >> 6] = contrib;
  __syncthreads();
  if (t == 0) bsum[blockIdx.x] = (red[0] + red[1]) + (red[2] + red[3]);
}

// ---------------- kernel 4: mean of 32 block sums ----------------
__global__ __launch_bounds__(64) void k_mean(const float* __restrict__ bsum,
                                             float* __restrict__ out) {
  float s = (threadIdx.x < 32) ? bsum[threadIdx.x] : 0.0f;
  s = wave_sum(s);
  if (threadIdx.x == 0) out[0] = s * (1.0f / (float)BB);
}

extern "C" void kernel_launch(void* const* d_in, const int* in_sizes, int n_in,
                              void* d_out, int out_size, void* d_ws, size_t ws_size,
                              hipStream_t stream) {
  const float* feat = (const float*)d_in[0];
  const float* feat_old = (const float*)d_in[1];
  const int* targets = (const int*)d_in[2];
  float* out = (float*)d_out;
  char* ws = (char*)d_ws;

  s8* fn8 = (s8*)ws;                                             // 2 MB
  s8* fo8 = (s8*)(ws + 2u * 1024 * 1024);                        // 2 MB
  float* pos = (float*)(ws + 4u * 1024 * 1024);                  // 16 KB
  float* partial = (float*)(ws + 4u * 1024 * 1024 + 16 * 1024);  // 512 KB
  float* bsum = (float*)(ws + 4u * 1024 * 1024 + 544 * 1024);    // 128 B

  k_norm<<<BB / 4, 256, 0, stream>>>(feat, feat_old, fn8, fo8, pos);
  k_fused<<<512, 512, 0, stream>>>(fn8, fo8, targets, partial);
  k_final<<<32, 256, 0, stream>>>(partial, pos, bsum);
  k_mean<<<1, 64, 0, stream>>>(bsum, out);
}

// Round 17
// 43.942 us; speedup vs baseline: 1.5195x; 1.0011x over previous
//
#include <hip/hip_runtime.h>
#include <hip/hip_bf16.h>

#define BB 4096
#define DD 512

typedef unsigned short u16;
typedef unsigned int u32;
typedef signed char s8;

using f32x4 = __attribute__((ext_vector_type(4))) float;
using i32x4 = __attribute__((ext_vector_type(4))) int;

// int8 quant: q = rint(x_norm * QS); exact i32 dot, s ~= acc / QS^2.
// p = exp2((s-1)*100*log2e + 64) = exp2(acc*CEXPQ + EOFF); lse = 100 - 64*ln2 + ln(sum p)
constexpr float QS = 400.0f;
constexpr float CEXP = 144.26950408889634f;          // 100 * log2(e)
constexpr float CEXPQ = CEXP / (QS * QS);            // dequant folded in
constexpr float EOFF = 64.0f - 144.26950408889634f;  // bias - CEXP
constexpr float LN2 = 0.6931471805599453f;
constexpr float LSE_BASE = 100.0f - 64.0f * 0.6931471805599453f;

__device__ __forceinline__ float wave_sum(float v) {
#pragma unroll
  for (int m = 1; m < 64; m <<= 1) v += __shfl_xor(v, m);
  return v;
}

// async global->LDS, 16B per lane. LDS dest is wave-uniform base + lane*16.
__device__ __forceinline__ void gload16(const void* g, const void* l) {
  __builtin_amdgcn_global_load_lds(
      (const __attribute__((address_space(1))) void*)g,
      (__attribute__((address_space(3))) void*)(const_cast<void*>(l)), 16, 0, 0);
}

// raw barrier (no vmcnt/lgkmcnt drain); memory clobbers pin memory ops to their side
__device__ __forceinline__ void barrier_raw() {
  asm volatile("" ::: "memory");
  __builtin_amdgcn_s_barrier();
  asm volatile("" ::: "memory");
}

__device__ __forceinline__ u32 q4(float a, float b, float c, float d, float s) {
  const int qa = (int)rintf(fminf(fmaxf(a * s, -127.0f), 127.0f));
  const int qb = (int)rintf(fminf(fmaxf(b * s, -127.0f), 127.0f));
  const int qc = (int)rintf(fminf(fmaxf(c * s, -127.0f), 127.0f));
  const int qd = (int)rintf(fminf(fmaxf(d * s, -127.0f), 127.0f));
  return (qa & 0xff) | ((qb & 0xff) << 8) | ((qc & 0xff) << 16) | ((qd & 0xff) << 24);
}

// ---------------- kernel 1: row L2-normalize (fp32) -> int8 (scale QS), fp32 pos ----------------
__global__ __launch_bounds__(256) void k_norm(const float* __restrict__ feat,
                                              const float* __restrict__ feat_old,
                                              s8* __restrict__ fn8, s8* __restrict__ fo8,
                                              float* __restrict__ pos) {
  const int i = blockIdx.x * 4 + (threadIdx.x >> 6);
  const int t = threadIdx.x & 63;
  const float4 x0 = *(const float4*)(feat + (size_t)i * DD + t * 4);
  const float4 x1 = *(const float4*)(feat + (size_t)i * DD + 256 + t * 4);
  const float4 y0 = *(const float4*)(feat_old + (size_t)i * DD + t * 4);
  const float4 y1 = *(const float4*)(feat_old + (size_t)i * DD + 256 + t * 4);
  float sx = x0.x * x0.x + x0.y * x0.y + x0.z * x0.z + x0.w * x0.w +
             x1.x * x1.x + x1.y * x1.y + x1.z * x1.z + x1.w * x1.w;
  float sy = y0.x * y0.x + y0.y * y0.y + y0.z * y0.z + y0.w * y0.w +
             y1.x * y1.x + y1.y * y1.y + y1.z * y1.z + y1.w * y1.w;
  float sxy = x0.x * y0.x + x0.y * y0.y + x0.z * y0.z + x0.w * y0.w +
              x1.x * y1.x + x1.y * y1.y + x1.z * y1.z + x1.w * y1.w;
  sx = wave_sum(sx);
  sy = wave_sum(sy);
  sxy = wave_sum(sxy);
  const float inx = 1.0f / fmaxf(sqrtf(sx), 1e-12f);
  const float iny = 1.0f / fmaxf(sqrtf(sy), 1e-12f);
  const float sxq = inx * QS, syq = iny * QS;
  u32* px0 = (u32*)(fn8 + (size_t)i * DD + t * 4);
  u32* px1 = (u32*)(fn8 + (size_t)i * DD + 256 + t * 4);
  u32* py0 = (u32*)(fo8 + (size_t)i * DD + t * 4);
  u32* py1 = (u32*)(fo8 + (size_t)i * DD + 256 + t * 4);
  *px0 = q4(x0.x, x0.y, x0.z, x0.w, sxq);
  *px1 = q4(x1.x, x1.y, x1.z, x1.w, sxq);
  *py0 = q4(y0.x, y0.y, y0.z, y0.w, syq);
  *py1 = q4(y1.x, y1.y, y1.z, y1.w, syq);
  if (t == 0) pos[i] = sxy * inx * iny;  // exact fp32 positive logit
}

// ---------------- kernel 2: fused dual-GEMM, int8 MFMA (R9 champion + unroll) ----------------
// 512 blocks = 16 mt x 32 nt (XCD-swizzled, EXACTLY 2 rounds of 256 CUs - no tail).
// 512 threads = 8 waves: wr = wid&3 (64-row M quarter), sel = wid>>2 (B1=old / B2=new).
// Tile: A 256xK, B 128xK each. BK=64 -> 32 mfma_i32_16x16x64_i8 per wave per K-tile.
// LDS 64 KB dbuf (2 blocks/CU co-resident with VGPR<=128). K-loop FULLY UNROLLED:
// static buffer selects, immediate ds/LDS offsets. All 4 stage loads issue at the top
// of the iteration (safe: end-of-iter barrier of t-1 means no wave still reads
// buf[nxt]); vmcnt(4) gates tile t's 4 loads with 4 new in flight, never draining.
__global__ __launch_bounds__(512, 2) void k_fused(const s8* __restrict__ fn8,
                                                  const s8* __restrict__ fo8,
                                                  const int* __restrict__ tgt,
                                                  float* __restrict__ partial) {
  __shared__ __align__(16) s8 lA[2][256 * 64];   // 32 KB
  __shared__ __align__(16) s8 lB1[2][128 * 64];  // 16 KB
  __shared__ __align__(16) s8 lB2[2][128 * 64];  // 16 KB

  const int tid = threadIdx.x;
  const int lane = tid & 63;
  const int wid = tid >> 6;   // 0..7
  const int wr = wid & 3;     // M quarter
  const int sel = wid >> 2;   // 0: B1(old)  1: B2(new)
  const int lrow = lane & 15;
  const int lkg = lane >> 4;

  // XCD-aware bijective swizzle (512 % 8 == 0)
  const int flat = blockIdx.x;
  const int swz = (flat & 7) * 64 + (flat >> 3);
  const int mt = swz >> 5, nt = swz & 31;
  const int row0 = mt * 256, jb = nt * 128;

  // staging: chunk = 16 rows x 64 B = 64 lanes x 16 B. lane l covers row 16c+(l>>2),
  // phys slot l&3; fetch LOGICAL slot (l&3)^((l>>3)&3) so the linear LDS write lands
  // in read-swizzled position (read: slot' = slot ^ ((row>>1)&3), row = 16c+(l>>2)).
  const int crow = lane >> 2;
  const int cofs = 16 * ((lane & 3) ^ ((lane >> 3) & 3));

  auto stageA = [&](s8* dst, int kk) {
#pragma unroll
    for (int i = 0; i < 2; ++i) {
      const int c = wid * 2 + i;  // 16 chunks cover 256 A rows
      gload16(fn8 + (size_t)(row0 + c * 16 + crow) * DD + kk + cofs, dst + c * 1024);
    }
  };
  auto stageB = [&](s8* d1, s8* d2, int kk) {
    const int c = wid;  // 8 chunks cover 128 B rows
    gload16(fo8 + (size_t)(jb + c * 16 + crow) * DD + kk + cofs, d1 + c * 1024);
    gload16(fn8 + (size_t)(jb + c * 16 + crow) * DD + kk + cofs, d2 + c * 1024);
  };

  i32x4 acc[4][8];
#pragma unroll
  for (int a = 0; a < 4; ++a)
#pragma unroll
    for (int b = 0; b < 8; ++b) acc[a][b] = (i32x4)(0);

  // prologue: stage tile 0 (4 loads/wave in flight)
  stageA(lA[0], 0);
  stageB(lB1[0], lB2[0], 0);

#pragma unroll
  for (int t = 0; t < 8; ++t) {
    const int cur = t & 1, nxt = cur ^ 1;  // compile-time after unroll
    const s8* cA = lA[cur];
    const s8* cB = sel ? lB2[cur] : lB1[cur];

    if (t < 7) {
      // issue ALL of tile t+1's loads up front (deep prefetch; WAR-safe via the
      // end-of-iteration barrier of t-1 -- no wave still reads buf[nxt])
      stageA(lA[nxt], (t + 1) * 64);
      stageB(lB1[nxt], lB2[nxt], (t + 1) * 64);
      asm volatile("s_waitcnt vmcnt(4)" ::: "memory");  // tile t's 4 landed; 4 fly on
    } else {
      asm volatile("s_waitcnt vmcnt(0)" ::: "memory");
    }
    barrier_raw();  // gate: tile t visible everywhere; prev reads done (end barrier)

    i32x4 av[4], bv[8];
#pragma unroll
    for (int f = 0; f < 4; ++f) {
      const int ar = wr * 64 + f * 16 + lrow;
      av[f] = *(const i32x4*)(cA + ar * 64 + ((lkg ^ ((ar >> 1) & 3)) * 16));
    }
#pragma unroll
    for (int f = 0; f < 8; ++f) {
      const int br = f * 16 + lrow;
      bv[f] = *(const i32x4*)(cB + br * 64 + ((lkg ^ ((br >> 1) & 3)) * 16));
    }
    __builtin_amdgcn_s_setprio(1);
#pragma unroll
    for (int fr = 0; fr < 4; ++fr)
#pragma unroll
      for (int fc = 0; fc < 8; ++fc)
        acc[fr][fc] = __builtin_amdgcn_mfma_i32_16x16x64_i8(av[fr], bv[fc], acc[fr][fc], 0, 0, 0);
    __builtin_amdgcn_s_setprio(0);
    barrier_raw();  // all waves done reading buf[cur] before t+1 overwrites it
  }

  // ---- epilogue: dequant + masked exp2, col-reduce, combine B1+B2, store partial ----
  const bool isN2O = (sel == 0);
  int tc[8];
#pragma unroll
  for (int fc = 0; fc < 8; ++fc) tc[fc] = tgt[jb + fc * 16 + lrow];
  float* rsum = (float*)lA;  // 2*256 floats; staging reads done
#pragma unroll
  for (int fr = 0; fr < 4; ++fr) {
#pragma unroll
    for (int reg = 0; reg < 4; ++reg) {
      const int gr = row0 + wr * 64 + fr * 16 + lkg * 4 + reg;
      const int trv = tgt[gr];
      float s = 0.0f;
#pragma unroll
      for (int fc = 0; fc < 8; ++fc) {
        const int gc = jb + fc * 16 + lrow;
        const float p = __builtin_amdgcn_exp2f(fmaf((float)acc[fr][fc][reg], CEXPQ, EOFF));
        // n2o: keep diagonal (stands in for the explicit pos column), drop same-label
        // n2n: drop all same-label (diagonal auto-dropped, labels equal)
        const bool keep = (trv != tc[fc]) || (isN2O && gr == gc);
        s += keep ? p : 0.0f;
      }
      s += __shfl_xor(s, 1);
      s += __shfl_xor(s, 2);
      s += __shfl_xor(s, 4);
      s += __shfl_xor(s, 8);
      if (lrow == 0) rsum[sel * 256 + wr * 64 + fr * 16 + lkg * 4 + reg] = s;
    }
  }
  asm volatile("s_waitcnt lgkmcnt(0)" ::: "memory");
  barrier_raw();
  if (tid < 256) {
    const float v = rsum[tid] + rsum[256 + tid];
    partial[(size_t)(row0 + tid) * 32 + nt] = v;
  }
}

// ---------------- kernel 3: per-row finalize (32 blocks) ----------------
__global__ __launch_bounds__(256) void k_final(const float* __restrict__ partial,
                                               const float* __restrict__ pos,
                                               float* __restrict__ bsum) {
  const int t = threadIdx.x;
  const int r = blockIdx.x * 128 + (t >> 1);
  const int half = t & 1;
  const float4* p = (const float4*)(partial + (size_t)r * 32 + half * 16);
  float v = 0.0f;
#pragma unroll
  for (int q = 0; q < 4; ++q) {
    const float4 a = p[q];
    v += (a.x + a.y) + (a.z + a.w);
  }
  v += __shfl_xor(v, 1);  // combine the two halves of the row
  float contrib = (half == 0)
                      ? (LSE_BASE + __builtin_amdgcn_logf(v) * LN2 - 100.0f * pos[r])
                      : 0.0f;
  contrib = wave_sum(contrib);
  __shared__ float red[4];
  if ((t & 63) == 0) red[t >> 6] = contrib;
  __syncthreads();
  if (t == 0) bsum[blockIdx.x] = (red[0] + red[1]) + (red[2] + red[3]);
}

// ---------------- kernel 4: mean of 32 block sums ----------------
__global__ __launch_bounds__(64) void k_mean(const float* __restrict__ bsum,
                                             float* __restrict__ out) {
  float s = (threadIdx.x < 32) ? bsum[threadIdx.x] : 0.0f;
  s = wave_sum(s);
  if (threadIdx.x == 0) out[0] = s * (1.0f / (float)BB);
}

extern "C" void kernel_launch(void* const* d_in, const int* in_sizes, int n_in,
                              void* d_out, int out_size, void* d_ws, size_t ws_size,
                              hipStream_t stream) {
  const float* feat = (const float*)d_in[0];
  const float* feat_old = (const float*)d_in[1];
  const int* targets = (const int*)d_in[2];
  float* out = (float*)d_out;
  char* ws = (char*)d_ws;

  s8* fn8 = (s8*)ws;                                             // 2 MB
  s8* fo8 = (s8*)(ws + 2u * 1024 * 1024);                        // 2 MB
  float* pos = (float*)(ws + 4u * 1024 * 1024);                  // 16 KB
  float* partial = (float*)(ws + 4u * 1024 * 1024 + 16 * 1024);  // 512 KB
  float* bsum = (float*)(ws + 4u * 1024 * 1024 + 544 * 1024);    // 128 B

  k_norm<<<BB / 4, 256, 0, stream>>>(feat, feat_old, fn8, fo8, pos);
  k_fused<<<512, 512, 0, stream>>>(fn8, fo8, targets, partial);
  k_final<<<32, 256, 0, stream>>>(partial, pos, bsum);
  k_mean<<<1, 64, 0, stream>>>(bsum, out);
}

// Round 18
// 41.896 us; speedup vs baseline: 1.5937x; 1.0488x over previous
//
#include <hip/hip_runtime.h>
#include <hip/hip_bf16.h>

#define BB 4096
#define DD 512

typedef unsigned short u16;
typedef unsigned int u32;
typedef signed char s8;

using f32x4 = __attribute__((ext_vector_type(4))) float;
using i32x4 = __attribute__((ext_vector_type(4))) int;

// int8 quant: q = rint(x_norm * QS); exact i32 dot, s ~= acc / QS^2.
// p = exp2((s-1)*100*log2e + 64) = exp2(acc*CEXPQ + EOFF); lse = 100 - 64*ln2 + ln(sum p)
constexpr float QS = 400.0f;
constexpr float CEXP = 144.26950408889634f;          // 100 * log2(e)
constexpr float CEXPQ = CEXP / (QS * QS);            // dequant folded in
constexpr float EOFF = 64.0f - 144.26950408889634f;  // bias - CEXP
constexpr float LN2 = 0.6931471805599453f;
constexpr float LSE_BASE = 100.0f - 64.0f * 0.6931471805599453f;

__device__ __forceinline__ float wave_sum(float v) {
#pragma unroll
  for (int m = 1; m < 64; m <<= 1) v += __shfl_xor(v, m);
  return v;
}

// async global->LDS, 16B per lane. LDS dest is wave-uniform base + lane*16.
__device__ __forceinline__ void gload16(const void* g, const void* l) {
  __builtin_amdgcn_global_load_lds(
      (const __attribute__((address_space(1))) void*)g,
      (__attribute__((address_space(3))) void*)(const_cast<void*>(l)), 16, 0, 0);
}

// raw barrier (no vmcnt/lgkmcnt drain); memory clobbers pin memory ops to their side
__device__ __forceinline__ void barrier_raw() {
  asm volatile("" ::: "memory");
  __builtin_amdgcn_s_barrier();
  asm volatile("" ::: "memory");
}

__device__ __forceinline__ u32 q4(float a, float b, float c, float d, float s) {
  const int qa = (int)rintf(fminf(fmaxf(a * s, -127.0f), 127.0f));
  const int qb = (int)rintf(fminf(fmaxf(b * s, -127.0f), 127.0f));
  const int qc = (int)rintf(fminf(fmaxf(c * s, -127.0f), 127.0f));
  const int qd = (int)rintf(fminf(fmaxf(d * s, -127.0f), 127.0f));
  return (qa & 0xff) | ((qb & 0xff) << 8) | ((qc & 0xff) << 16) | ((qd & 0xff) << 24);
}

// ---------------- kernel 1: row L2-normalize (fp32) -> int8 (scale QS), fp32 pos ----------------
// Also zeroes out[0] each call (k_final accumulates into it atomically; keeps graph
// replays self-contained).
__global__ __launch_bounds__(256) void k_norm(const float* __restrict__ feat,
                                              const float* __restrict__ feat_old,
                                              s8* __restrict__ fn8, s8* __restrict__ fo8,
                                              float* __restrict__ pos,
                                              float* __restrict__ out) {
  if (blockIdx.x == 0 && threadIdx.x == 0) out[0] = 0.0f;
  const int i = blockIdx.x * 4 + (threadIdx.x >> 6);
  const int t = threadIdx.x & 63;
  const float4 x0 = *(const float4*)(feat + (size_t)i * DD + t * 4);
  const float4 x1 = *(const float4*)(feat + (size_t)i * DD + 256 + t * 4);
  const float4 y0 = *(const float4*)(feat_old + (size_t)i * DD + t * 4);
  const float4 y1 = *(const float4*)(feat_old + (size_t)i * DD + 256 + t * 4);
  float sx = x0.x * x0.x + x0.y * x0.y + x0.z * x0.z + x0.w * x0.w +
             x1.x * x1.x + x1.y * x1.y + x1.z * x1.z + x1.w * x1.w;
  float sy = y0.x * y0.x + y0.y * y0.y + y0.z * y0.z + y0.w * y0.w +
             y1.x * y1.x + y1.y * y1.y + y1.z * y1.z + y1.w * y1.w;
  float sxy = x0.x * y0.x + x0.y * y0.y + x0.z * y0.z + x0.w * y0.w +
              x1.x * y1.x + x1.y * y1.y + x1.z * y1.z + x1.w * y1.w;
  sx = wave_sum(sx);
  sy = wave_sum(sy);
  sxy = wave_sum(sxy);
  const float inx = 1.0f / fmaxf(sqrtf(sx), 1e-12f);
  const float iny = 1.0f / fmaxf(sqrtf(sy), 1e-12f);
  const float sxq = inx * QS, syq = iny * QS;
  u32* px0 = (u32*)(fn8 + (size_t)i * DD + t * 4);
  u32* px1 = (u32*)(fn8 + (size_t)i * DD + 256 + t * 4);
  u32* py0 = (u32*)(fo8 + (size_t)i * DD + t * 4);
  u32* py1 = (u32*)(fo8 + (size_t)i * DD + 256 + t * 4);
  *px0 = q4(x0.x, x0.y, x0.z, x0.w, sxq);
  *px1 = q4(x1.x, x1.y, x1.z, x1.w, sxq);
  *py0 = q4(y0.x, y0.y, y0.z, y0.w, syq);
  *py1 = q4(y1.x, y1.y, y1.z, y1.w, syq);
  if (t == 0) pos[i] = sxy * inx * iny;  // exact fp32 positive logit
}

// ---------------- kernel 2: fused dual-GEMM, int8 MFMA (R9 champion, no setprio) ----------------
// 512 blocks = 16 mt x 32 nt (XCD-swizzled, exactly 2 rounds of 256 CUs - no tail).
// 512 threads = 8 waves: wr = wid&3 (64-row M quarter), sel = wid>>2 (B1=old / B2=new).
// Tile: A 256xK, B 128xK each. BK=64 -> 32 mfma_i32_16x16x64_i8 per wave per K-tile.
// LDS 64 KB dbuf; VGPR 128 -> 2 blocks/CU co-resident. setprio removed (m190: slightly
// negative on lockstep barrier-synced GEMM; only pays on phase-split schedules).
__global__ __launch_bounds__(512, 2) void k_fused(const s8* __restrict__ fn8,
                                                  const s8* __restrict__ fo8,
                                                  const int* __restrict__ tgt,
                                                  float* __restrict__ partial) {
  __shared__ __align__(16) s8 lA[2][256 * 64];   // 32 KB
  __shared__ __align__(16) s8 lB1[2][128 * 64];  // 16 KB
  __shared__ __align__(16) s8 lB2[2][128 * 64];  // 16 KB

  const int tid = threadIdx.x;
  const int lane = tid & 63;
  const int wid = tid >> 6;   // 0..7
  const int wr = wid & 3;     // M quarter
  const int sel = wid >> 2;   // 0: B1(old)  1: B2(new)
  const int lrow = lane & 15;
  const int lkg = lane >> 4;

  // XCD-aware bijective swizzle (512 % 8 == 0)
  const int flat = blockIdx.x;
  const int swz = (flat & 7) * 64 + (flat >> 3);
  const int mt = swz >> 5, nt = swz & 31;
  const int row0 = mt * 256, jb = nt * 128;

  // staging: chunk = 16 rows x 64 B = 64 lanes x 16 B. lane l covers row 16c+(l>>2),
  // phys slot l&3; fetch LOGICAL slot (l&3)^((l>>3)&3) so the linear LDS write lands
  // in read-swizzled position (read: slot' = slot ^ ((row>>1)&3), row = 16c+(l>>2)).
  const int crow = lane >> 2;
  const int cofs = 16 * ((lane & 3) ^ ((lane >> 3) & 3));

  auto stageA = [&](s8* dst, int kk) {
#pragma unroll
    for (int i = 0; i < 2; ++i) {
      const int c = wid * 2 + i;  // 16 chunks cover 256 A rows
      gload16(fn8 + (size_t)(row0 + c * 16 + crow) * DD + kk + cofs, dst + c * 1024);
    }
  };
  auto stageB = [&](s8* d1, s8* d2, int kk) {
    const int c = wid;  // 8 chunks cover 128 B rows
    gload16(fo8 + (size_t)(jb + c * 16 + crow) * DD + kk + cofs, d1 + c * 1024);
    gload16(fn8 + (size_t)(jb + c * 16 + crow) * DD + kk + cofs, d2 + c * 1024);
  };

  i32x4 acc[4][8];
#pragma unroll
  for (int a = 0; a < 4; ++a)
#pragma unroll
    for (int b = 0; b < 8; ++b) acc[a][b] = (i32x4)(0);

  // prologue: stage tile 0 (4 loads/wave in flight)
  stageA(lA[0], 0);
  stageB(lB1[0], lB2[0], 0);

  for (int t = 0; t < 8; ++t) {
    const int cur = t & 1, nxt = cur ^ 1;
    const s8* cA = lA[cur];
    const s8* cB = sel ? lB2[cur] : lB1[cur];

    if (t < 7) {
      stageA(lA[nxt], (t + 1) * 64);
      asm volatile("s_waitcnt vmcnt(2)" ::: "memory");  // tile t's 4 landed; 2 new fly on
    } else {
      asm volatile("s_waitcnt vmcnt(0)" ::: "memory");
    }
    barrier_raw();  // gate: tile t visible everywhere; prev reads done (end barrier)

    i32x4 av[4], bv[8];
#pragma unroll
    for (int f = 0; f < 4; ++f) {
      const int ar = wr * 64 + f * 16 + lrow;
      av[f] = *(const i32x4*)(cA + ar * 64 + ((lkg ^ ((ar >> 1) & 3)) * 16));
    }
#pragma unroll
    for (int f = 0; f < 8; ++f) {
      const int br = f * 16 + lrow;
      bv[f] = *(const i32x4*)(cB + br * 64 + ((lkg ^ ((br >> 1) & 3)) * 16));
    }
    if (t < 7) stageB(lB1[nxt], lB2[nxt], (t + 1) * 64);  // 2 more in flight for t+1
#pragma unroll
    for (int fr = 0; fr < 4; ++fr)
#pragma unroll
      for (int fc = 0; fc < 8; ++fc)
        acc[fr][fc] = __builtin_amdgcn_mfma_i32_16x16x64_i8(av[fr], bv[fc], acc[fr][fc], 0, 0, 0);
    barrier_raw();  // all waves done reading buf[cur] before t+1 overwrites it
  }

  // ---- epilogue: dequant + masked exp2, col-reduce, combine B1+B2, store partial ----
  const bool isN2O = (sel == 0);
  int tc[8];
#pragma unroll
  for (int fc = 0; fc < 8; ++fc) tc[fc] = tgt[jb + fc * 16 + lrow];
  float* rsum = (float*)lA;  // 2*256 floats; staging reads done
#pragma unroll
  for (int fr = 0; fr < 4; ++fr) {
#pragma unroll
    for (int reg = 0; reg < 4; ++reg) {
      const int gr = row0 + wr * 64 + fr * 16 + lkg * 4 + reg;
      const int trv = tgt[gr];
      float s = 0.0f;
#pragma unroll
      for (int fc = 0; fc < 8; ++fc) {
        const int gc = jb + fc * 16 + lrow;
        const float p = __builtin_amdgcn_exp2f(fmaf((float)acc[fr][fc][reg], CEXPQ, EOFF));
        // n2o: keep diagonal (stands in for the explicit pos column), drop same-label
        // n2n: drop all same-label (diagonal auto-dropped, labels equal)
        const bool keep = (trv != tc[fc]) || (isN2O && gr == gc);
        s += keep ? p : 0.0f;
      }
      s += __shfl_xor(s, 1);
      s += __shfl_xor(s, 2);
      s += __shfl_xor(s, 4);
      s += __shfl_xor(s, 8);
      if (lrow == 0) rsum[sel * 256 + wr * 64 + fr * 16 + lkg * 4 + reg] = s;
    }
  }
  asm volatile("s_waitcnt lgkmcnt(0)" ::: "memory");
  barrier_raw();
  if (tid < 256) {
    const float v = rsum[tid] + rsum[256 + tid];
    partial[(size_t)(row0 + tid) * 32 + nt] = v;
  }
}

// ---------------- kernel 3: per-row finalize + fused mean (32 blocks) ----------------
// Each block handles 128 rows; block total accumulated into out[0] via one atomicAdd
// per block (32 adds total; out zeroed by k_norm). Replaces separate k_final+k_mean.
__global__ __launch_bounds__(256) void k_final(const float* __restrict__ partial,
                                               const float* __restrict__ pos,
                                               float* __restrict__ out) {
  const int t = threadIdx.x;
  const int r = blockIdx.x * 128 + (t >> 1);
  const int half = t & 1;
  const float4* p = (const float4*)(partial + (size_t)r * 32 + half * 16);
  float v = 0.0f;
#pragma unroll
  for (int q = 0; q < 4; ++q) {
    const float4 a = p[q];
    v += (a.x + a.y) + (a.z + a.w);
  }
  v += __shfl_xor(v, 1);  // combine the two halves of the row
  float contrib = (half == 0)
                      ? (LSE_BASE + __builtin_amdgcn_logf(v) * LN2 - 100.0f * pos[r])
                      : 0.0f;
  contrib = wave_sum(contrib);
  __shared__ float red[4];
  if ((t & 63) == 0) red[t >> 6] = contrib;
  __syncthreads();
  if (t == 0)
    atomicAdd(out, ((red[0] + red[1]) + (red[2] + red[3])) * (1.0f / (float)BB));
}

extern "C" void kernel_launch(void* const* d_in, const int* in_sizes, int n_in,
                              void* d_out, int out_size, void* d_ws, size_t ws_size,
                              hipStream_t stream) {
  const float* feat = (const float*)d_in[0];
  const float* feat_old = (const float*)d_in[1];
  const int* targets = (const int*)d_in[2];
  float* out = (float*)d_out;
  char* ws = (char*)d_ws;

  s8* fn8 = (s8*)ws;                                             // 2 MB
  s8* fo8 = (s8*)(ws + 2u * 1024 * 1024);                        // 2 MB
  float* pos = (float*)(ws + 4u * 1024 * 1024);                  // 16 KB
  float* partial = (float*)(ws + 4u * 1024 * 1024 + 16 * 1024);  // 512 KB

  k_norm<<<BB / 4, 256, 0, stream>>>(feat, feat_old, fn8, fo8, pos, out);
  k_fused<<<512, 512, 0, stream>>>(fn8, fo8, targets, partial);
  k_final<<<32, 256, 0, stream>>>(partial, pos, out);
}